// Round 20
// baseline (345.266 us; speedup 1.0000x reference)
//
#include <hip/hip_runtime.h>
#include <hip/hip_bf16.h>
#include <stdint.h>

// SNN forward v6: 2-plane i8 MFMA GEMM, 3-slot LDS ring, DEPTH-2 prefetch
// (issue tile i+2 post-barrier_i; wait vmcnt(3) pre-barrier => each tile has
// ~2 iterations to land; never drain below 3 in-loop), 1 barrier/iter.
// f32 LIF flag-scan (EPS=3e-4, Hoeffding-certified) + bit-skip BLAS-order
// fixup (r14-r19 validated: ref = OpenBLAS ascending-k chains, KC=384 folds).
//
// Ring safety (depth-2): loads for tile i+2 (slot (i+2)%3 = (i-1)%3) are
// issued AFTER barrier_i; any wave past barrier_i has issued its iter-(i-1)
// MFMAs, which required lgkmcnt on the iter-(i-1) ds_reads of that slot =>
// no read-write race. vmcnt(3) before barrier_i forces tile i complete
// (only tile i+1's 3 loads may remain in flight).
//
// d_out (f32): [spk1 | mem1 | spk2 | mem2] x 16777216. GEMM writes cur f32
// into spk regions; lif_flag overwrites; flagged cols recomputed bit-exact.
// d_ws: Bp 8MB | S 32MB | maskR 4MB | list 2MB | count.

#define REGION 16777216
#define BN_ELEMS 262144
#define FLAG_EPS 3e-4f

typedef __attribute__((ext_vector_type(4))) int v4i;

typedef __attribute__((address_space(1))) const void gvoid_t;
typedef __attribute__((address_space(3))) void svoid_t;

__device__ __forceinline__ void gload_lds16(const void* g, void* l) {
  __builtin_amdgcn_global_load_lds((gvoid_t*)g, (svoid_t*)l, 16, 0, 0);
}

// ---- fused prep: blocks 0..2047 cvt+mask; 2048..18431 digit-pack ----
__global__ void prep_kernel(const float* __restrict__ spikes, int* __restrict__ s4,
                            unsigned long long* __restrict__ maskR,
                            int* __restrict__ count,
                            const float* __restrict__ W1, const float* __restrict__ W2,
                            signed char* __restrict__ Bp) {
  int blk = blockIdx.x;
  if (blk < 2048) {
    int id = blk * 256 + threadIdx.x;         // 16384 rows * 32 chunks
    if (id == 0) *count = 0;
    int row = id >> 5, c = id & 31;
    const float4* p = (const float4*)(spikes + (long long)row * 2048 + c * 64);
    unsigned long long m = 0;
    int* sd = s4 + (row * 2048 + c * 64) / 4;
#pragma unroll
    for (int q = 0; q < 16; ++q) {
      float4 v = p[q];
      int b0 = (v.x != 0.f), b1 = (v.y != 0.f), b2 = (v.z != 0.f), b3 = (v.w != 0.f);
      sd[q] = b0 | (b1 << 8) | (b2 << 16) | (b3 << 24);
      m |= (unsigned long long)b0 << (4 * q);
      m |= (unsigned long long)b1 << (4 * q + 1);
      m |= (unsigned long long)b2 << (4 * q + 2);
      m |= (unsigned long long)b3 << (4 * q + 3);
    }
    maskR[(long long)row * 32 + c] = m;
  } else {
    int idx = (blk - 2048) * 256 + threadIdx.x;   // 2048*2048
    int n = idx >> 11, k = idx & 2047;
    float w = (n < 1024) ? W1[n * 2048 + k] : W2[(n - 1024) * 2048 + k];
    int V = (int)rintf(w * 1048576.0f);       // 2^20; |V| <= 23270
    int d0 = ((V + 128) & 255) - 128;
    int d1 = (V - d0) >> 8;                   // |d1| <= 91
    signed char* row = Bp + (long long)n * 4096;
    row[k]        = (signed char)d1;   // seg 0
    row[2048 + k] = (signed char)d0;   // seg 1
  }
}

// ---- 2-plane i8 GEMM, ring-3, depth-2 prefetch, 1 barrier/iter ----
__global__ __launch_bounds__(512) void gemm_snn(const signed char* __restrict__ S,
                                                const signed char* __restrict__ Bp,
                                                float* __restrict__ out) {
  __shared__ __align__(16) signed char As[3 * 8192];
  __shared__ __align__(16) signed char Bs0[3 * 8192];
  __shared__ __align__(16) signed char Bs1[3 * 8192];
  const int tid = threadIdx.x;
  const int wv = tid >> 6, ln = tid & 63;

  int bid = blockIdx.x;                        // XCD swizzle (1024 = 8*128)
  int swz = (bid & 7) * 128 + (bid >> 3);
  const int bm = swz >> 3;    // 0..127
  const int bn = swz & 7;     // 0..7
  const int wr = wv >> 2, wc = wv & 3;         // 2M x 4N waves

  const int srow = wv * 16 + (ln >> 2);
  const int scolb = ((ln & 3) ^ ((srow >> 1) & 3)) * 16;   // pre-inverse swizzle
  const signed char* aSrc  = S  + (long long)(bm * 128 + srow) * 2048 + scolb;
  const signed char* b0Src = Bp + (long long)(bn * 128 + srow) * 4096 + scolb;
  const signed char* b1Src = Bp + (long long)(1024 + bn * 128 + srow) * 4096 + scolb;
  const int ldsW = wv * 1024;                  // wave-uniform LDS dst base

  const int l15 = ln & 15, l4 = ln >> 4;
  int aOff[4], bOff[2];
#pragma unroll
  for (int f = 0; f < 4; ++f) {
    int r = wr * 64 + f * 16 + l15;
    aOff[f] = r * 64 + (l4 ^ ((r >> 1) & 3)) * 16;   // swizzled read
  }
#pragma unroll
  for (int g = 0; g < 2; ++g) {
    int r = wc * 32 + g * 16 + l15;
    bOff[g] = r * 64 + (l4 ^ ((r >> 1) & 3)) * 16;
  }

  v4i acc[2][4][2];
#pragma unroll
  for (int L = 0; L < 2; ++L)
#pragma unroll
    for (int f = 0; f < 4; ++f)
#pragma unroll
      for (int g = 0; g < 2; ++g) acc[L][f][g] = (v4i){0, 0, 0, 0};

  // prologue: stage tiles 0 and 1 into slots 0,1
  gload_lds16(aSrc, &As[ldsW]);
  gload_lds16(b0Src, &Bs0[ldsW]);
  gload_lds16(b1Src, &Bs1[ldsW]);
  gload_lds16(aSrc + 64, &As[8192 + ldsW]);
  gload_lds16(b0Src + 64, &Bs0[8192 + ldsW]);
  gload_lds16(b1Src + 64, &Bs1[8192 + ldsW]);

#pragma unroll 1
  for (int i = 0; i < 64; ++i) {
    if (i < 63) {
      asm volatile("s_waitcnt vmcnt(3)" ::: "memory");  // tile i landed
    } else {
      asm volatile("s_waitcnt vmcnt(0)" ::: "memory");
    }
    __builtin_amdgcn_sched_barrier(0);
    __builtin_amdgcn_s_barrier();              // single barrier per iteration
    __builtin_amdgcn_sched_barrier(0);

    if (i < 62) {                              // depth-2: issue tile i+2 now
      const int ii = i + 2;
      const int kc = (ii & 31) * 64, so = (ii >> 5) * 2048;
      const int wb = (ii % 3) * 8192 + ldsW;
      gload_lds16(aSrc + kc, &As[wb]);
      gload_lds16(b0Src + so + kc, &Bs0[wb]);
      gload_lds16(b1Src + so + kc, &Bs1[wb]);
    }

    if (i == 32) {                             // Horner fold between planes
#pragma unroll
      for (int L = 0; L < 2; ++L)
#pragma unroll
        for (int f = 0; f < 4; ++f)
#pragma unroll
          for (int g = 0; g < 2; ++g)
#pragma unroll
            for (int r = 0; r < 4; ++r) acc[L][f][g][r] *= 256;
    }

    const int rb = (i % 3) * 8192;
    v4i a[4], b0[2], b1[2];
#pragma unroll
    for (int f = 0; f < 4; ++f) a[f] = *(const v4i*)&As[rb + aOff[f]];
#pragma unroll
    for (int g = 0; g < 2; ++g) b0[g] = *(const v4i*)&Bs0[rb + bOff[g]];
#pragma unroll
    for (int g = 0; g < 2; ++g) b1[g] = *(const v4i*)&Bs1[rb + bOff[g]];
#pragma unroll
    for (int f = 0; f < 4; ++f)
#pragma unroll
      for (int g = 0; g < 2; ++g) {
        acc[0][f][g] = __builtin_amdgcn_mfma_i32_16x16x64_i8(a[f], b0[g], acc[0][f][g], 0, 0, 0);
        acc[1][f][g] = __builtin_amdgcn_mfma_i32_16x16x64_i8(a[f], b1[g], acc[1][f][g], 0, 0, 0);
      }
  }

#pragma unroll
  for (int L = 0; L < 2; ++L) {
    float* spkBase = out + (L ? 2LL * REGION : 0);
#pragma unroll
    for (int f = 0; f < 4; ++f)
#pragma unroll
      for (int g = 0; g < 2; ++g) {
        int row = bm * 128 + wr * 64 + f * 16 + l4 * 4;
        int col = bn * 128 + wc * 32 + g * 16 + l15;
#pragma unroll
        for (int r = 0; r < 4; ++r)
          spkBase[(long long)(row + r) * 1024 + col] =
              (float)((double)acc[L][f][g][r] * (1.0 / 1048576.0));
      }
  }
}

// ---- f32 LIF scan, both layers per thread; unroll 4 for load batching ----
__global__ void lif_flag(float* __restrict__ out, int* __restrict__ list,
                         int* __restrict__ count) {
  int j = blockIdx.x * 256 + threadIdx.x;     // 0..262143
  float* spk1 = out;
  float* mem1 = out + 1LL * REGION;
  float* spk2 = out + 2LL * REGION;
  float* mem2 = out + 3LL * REGION;
  float ma = 0.0f, mb = 0.0f;
  bool fa = false, fb = false;
#pragma unroll 4
  for (int t = 0; t < 64; ++t) {
    int k = t * BN_ELEMS + j;
    float ca = spk1[k];
    float cb = spk2[k];
    float ra = (ma > 1.0f) ? 1.0f : 0.0f;
    float rb = (mb > 1.0f) ? 1.0f : 0.0f;
    ma = __fsub_rn(__fadd_rn(__fmul_rn(0.9f, ma), ca), ra);
    mb = __fsub_rn(__fadd_rn(__fmul_rn(0.9f, mb), cb), rb);
    fa |= (fabsf(ma - 1.0f) < FLAG_EPS);
    fb |= (fabsf(mb - 1.0f) < FLAG_EPS);
    spk1[k] = (ma > 1.0f) ? 1.0f : 0.0f;
    mem1[k] = ma;
    spk2[k] = (mb > 1.0f) ? 1.0f : 0.0f;
    mem2[k] = mb;
  }
  if (fa) { int q = atomicAdd(count, 1); list[q] = j; }
  if (fb) { int q = atomicAdd(count, 1); list[q] = BN_ELEMS + j; }
}

// ---- fixup: 4 waves/block, one column/wave, bit-skip BLAS-order chain ----
__global__ __launch_bounds__(256) void fixup_kernel(
    const unsigned long long* __restrict__ maskR,
    const float* __restrict__ W1, const float* __restrict__ W2,
    const int* __restrict__ list, const int* __restrict__ count,
    float* __restrict__ out) {
  __shared__ float ws[4][2048];
  __shared__ float curs[4][64];
  const int wv = threadIdx.x >> 6, ln = threadIdx.x & 63;
  const int cnt = *count;
  for (int li = blockIdx.x * 4 + wv; li < cnt; li += gridDim.x * 4) {
    int idx = list[li];
    int layer = idx >> 18;
    int j = idx & (BN_ELEMS - 1);
    int n = j & 1023, b = j >> 10;
    const float* wrow = (layer ? W2 : W1) + (long long)n * 2048;
#pragma unroll
    for (int i = 0; i < 8; ++i)
      ((float4*)ws[wv])[ln + 64 * i] = ((const float4*)wrow)[ln + 64 * i];
    asm volatile("s_waitcnt lgkmcnt(0)" ::: "memory");   // wave-local LDS fence

    const unsigned long long* mr = maskR + (long long)(ln * 256 + b) * 32;
    float total = 0.0f, pacc = 0.0f;
    bool first = true;
#pragma unroll 1
    for (int c = 0; c < 32; ++c) {
      if (c == 6 || c == 12 || c == 18 || c == 24 || c == 30) {  // k = 384p
        total = first ? pacc : __fadd_rn(total, pacc);
        first = false; pacc = 0.0f;
      }
      unsigned long long msk = mr[c];
      unsigned mlo = (unsigned)msk, mhi = (unsigned)(msk >> 32);
      const float* wb = ws[wv] + c * 64;
      while (mlo) {                            // ascending q: exact BLAS order;
        int q = __builtin_ctz(mlo);            // skipping +0.0f adds is bitwise
        mlo &= mlo - 1;                        // identity (pacc never -0)
        pacc = __fadd_rn(pacc, wb[q]);
      }
      while (mhi) {
        int q = __builtin_ctz(mhi);
        mhi &= mhi - 1;
        pacc = __fadd_rn(pacc, wb[32 + q]);
      }
    }
    total = first ? pacc : __fadd_rn(total, pacc);
    curs[wv][ln] = total;
    asm volatile("s_waitcnt lgkmcnt(0)" ::: "memory");

    float m = 0.0f, myspk = 0.0f, mymem = 0.0f;
#pragma unroll 1
    for (int tt = 0; tt < 64; ++tt) {
      float c2 = curs[wv][tt];
      float reset = (m > 1.0f) ? 1.0f : 0.0f;
      m = __fsub_rn(__fadd_rn(__fmul_rn(0.9f, m), c2), reset);
      if (tt == ln) { myspk = (m > 1.0f) ? 1.0f : 0.0f; mymem = m; }
    }
    float* spkR = out + (layer ? 2LL * REGION : 0);
    float* memR = out + (layer ? 3LL * REGION : 1LL * REGION);
    spkR[ln * BN_ELEMS + j] = myspk;
    memR[ln * BN_ELEMS + j] = mymem;
  }
}

extern "C" void kernel_launch(void* const* d_in, const int* in_sizes, int n_in,
                              void* d_out, int out_size, void* d_ws, size_t ws_size,
                              hipStream_t stream) {
  const float* spikes = (const float*)d_in[0];
  const float* W1 = (const float*)d_in[1];
  const float* W2 = (const float*)d_in[2];
  float* out = (float*)d_out;
  signed char* Bp = (signed char*)d_ws;                              // 8,388,608 B
  signed char* S  = (signed char*)d_ws + 8388608;                    // 33,554,432 B
  unsigned long long* maskR = (unsigned long long*)((char*)d_ws + 41943040);  // 4MB
  int* list  = (int*)((char*)d_ws + 46137344);                       // 2MB
  int* count = (int*)((char*)d_ws + 48234496);

  prep_kernel<<<18432, 256, 0, stream>>>(spikes, (int*)S, maskR, count, W1, W2, Bp);
  gemm_snn<<<1024, 512, 0, stream>>>(S, Bp, out);
  lif_flag<<<1024, 256, 0, stream>>>(out, list, count);
  fixup_kernel<<<4096, 256, 0, stream>>>(maskR, W1, W2, list, count, out);
}